// Round 1
// baseline (918.398 us; speedup 1.0000x reference)
//
#include <hip/hip_runtime.h>
#include <hip/hip_bf16.h>
#include <cstdint>
#include <cstddef>

#define HIDD 1536
#define NB 32
#define NT 32
#define AD 32

typedef __attribute__((ext_vector_type(8))) __bf16 bf16x8;
typedef __attribute__((ext_vector_type(4))) float floatx4;

__device__ __forceinline__ unsigned short f2bf(float f) {
    union { float f; uint32_t u; } v; v.f = f;
    uint32_t r = v.u + 0x7fffu + ((v.u >> 16) & 1u);   // RNE
    return (unsigned short)(r >> 16);
}

__device__ __forceinline__ uint32_t pack2(float lo, float hi) {
    return (uint32_t)f2bf(lo) | ((uint32_t)f2bf(hi) << 16);
}

// ---------------------------------------------------------------------------
// Kernel 1: x = [actions @ W1[c] + b1[c],  sinusoidal(ts)]   -> bf16 (B,T,3072)
// ---------------------------------------------------------------------------
__global__ __launch_bounds__(256) void build_x_kernel(
    const float* __restrict__ actions,   // (B,T,32)
    const int*   __restrict__ timesteps, // (B,)
    const int*   __restrict__ cat_ids,   // (B,)
    const float* __restrict__ W1,        // (C,32,1536)
    const float* __restrict__ b1,        // (C,1536)
    unsigned short* __restrict__ Xout)   // (B,T,3072) bf16
{
    const int b = blockIdx.z, t = blockIdx.y;
    const int j = blockIdx.x * 256 + threadIdx.x;
    __shared__ float as[AD];
    if (threadIdx.x < AD) as[threadIdx.x] = actions[(b * NT + t) * AD + threadIdx.x];
    __syncthreads();

    float val;
    if (j < HIDD) {
        const int c = cat_ids[b];
        const float* w = W1 + ((size_t)c * AD) * HIDD + j;
        float acc = b1[c * HIDD + j];
        #pragma unroll
        for (int k = 0; k < AD; ++k) acc += as[k] * w[(size_t)k * HIDD];
        val = acc;
    } else {
        const int jj = j - HIDD;
        const int i = jj >> 1;
        const float div = expf(-9.210340371976184f * (float)i * (1.0f / 768.0f));
        const float arg = (float)timesteps[b] * div;
        val = (jj & 1) ? cosf(arg) : sinf(arg);
    }
    Xout[((size_t)(b * NT + t)) * (2 * HIDD) + j] = f2bf(val);
}

// ---------------------------------------------------------------------------
// Kernel 2/3: per-sample GEMM  out[b] = act(X[b] @ W[cat_b] + bias[cat_b])
// M=32 (T), N=1536, K template. BN=64 per block, BK=64 per K-iter.
// W staged fp32->bf16 transposed [n][k] in LDS; MFMA 16x16x32 bf16.
// ---------------------------------------------------------------------------
template<int K, bool SWISH>
__global__ __launch_bounds__(256) void gemm_cat_kernel(
    const unsigned short* __restrict__ X,    // (B,32,K) bf16
    const float* __restrict__ W,             // (C,K,1536) fp32
    const float* __restrict__ bias,          // (C,1536) fp32
    const int*   __restrict__ cat_ids,       // (B,)
    unsigned short* __restrict__ OutBf,      // used if SWISH
    float* __restrict__ OutF)                // used if !SWISH
{
    const int b  = blockIdx.y;
    const int c  = cat_ids[b];
    const int n0 = blockIdx.x * 64;
    const int tid  = threadIdx.x;
    const int wave = tid >> 6;
    const int lane = tid & 63;

    __shared__ __align__(16) unsigned short Xs[32][72];
    __shared__ __align__(16) unsigned short Ws[64][72];

    floatx4 acc0 = {0.f, 0.f, 0.f, 0.f};
    floatx4 acc1 = {0.f, 0.f, 0.f, 0.f};

    const int xt = tid >> 3;          // 0..31 (row of X tile)
    const int xk = (tid & 7) * 8;     // 0..56 (k offset, 8 bf16 = 16B)

    const int wk_base = (tid >> 4) * 2;   // 0,2,..,30
    const int wn4     = (tid & 15) * 4;   // 0,4,..,60

    for (int kb = 0; kb < K / 64; ++kb) {
        // ---- stage X tile (32 x 64 bf16), b128 loads/stores, A-layout [t][k]
        {
            const uint4 xv = *reinterpret_cast<const uint4*>(
                X + ((size_t)(b * 32 + xt)) * K + kb * 64 + xk);
            *reinterpret_cast<uint4*>(&Xs[xt][xk]) = xv;
        }
        // ---- stage W tile (64 rows k x 64 cols n) fp32 -> bf16, transpose to [n][k]
        #pragma unroll
        for (int p = 0; p < 2; ++p) {
            const int k0 = wk_base + p * 32;
            const float* wsrc = W + ((size_t)c * K + (size_t)(kb * 64 + k0)) * HIDD + n0 + wn4;
            const float4 r0 = *reinterpret_cast<const float4*>(wsrc);
            const float4 r1 = *reinterpret_cast<const float4*>(wsrc + HIDD);
            *reinterpret_cast<uint32_t*>(&Ws[wn4 + 0][k0]) = pack2(r0.x, r1.x);
            *reinterpret_cast<uint32_t*>(&Ws[wn4 + 1][k0]) = pack2(r0.y, r1.y);
            *reinterpret_cast<uint32_t*>(&Ws[wn4 + 2][k0]) = pack2(r0.z, r1.z);
            *reinterpret_cast<uint32_t*>(&Ws[wn4 + 3][k0]) = pack2(r0.w, r1.w);
        }
        __syncthreads();

        // ---- MFMA: wave handles 16 cols (n = n0 + wave*16 + lane&15), M=32 as 2 tiles
        #pragma unroll
        for (int ks = 0; ks < 2; ++ks) {
            const bf16x8 a0 = *reinterpret_cast<const bf16x8*>(
                &Xs[lane & 15][ks * 32 + (lane >> 4) * 8]);
            const bf16x8 a1 = *reinterpret_cast<const bf16x8*>(
                &Xs[16 + (lane & 15)][ks * 32 + (lane >> 4) * 8]);
            const bf16x8 bw = *reinterpret_cast<const bf16x8*>(
                &Ws[wave * 16 + (lane & 15)][ks * 32 + (lane >> 4) * 8]);
            acc0 = __builtin_amdgcn_mfma_f32_16x16x32_bf16(a0, bw, acc0, 0, 0, 0);
            acc1 = __builtin_amdgcn_mfma_f32_16x16x32_bf16(a1, bw, acc1, 0, 0, 0);
        }
        __syncthreads();
    }

    // ---- epilogue: D layout col=lane&15, row=(lane>>4)*4+reg
    const int n_col = n0 + wave * 16 + (lane & 15);
    const float bv = bias[c * HIDD + n_col];
    const int quad = lane >> 4;
    #pragma unroll
    for (int r = 0; r < 4; ++r) {
        const int m0 = quad * 4 + r;
        float v0 = acc0[r] + bv;
        float v1 = acc1[r] + bv;
        if (SWISH) {
            v0 = v0 / (1.f + __expf(-v0));
            v1 = v1 / (1.f + __expf(-v1));
            OutBf[((size_t)(b * 32 + m0)) * HIDD + n_col] = f2bf(v0);
            OutBf[((size_t)(b * 32 + m0 + 16)) * HIDD + n_col] = f2bf(v1);
        } else {
            OutF[((size_t)(b * 32 + m0)) * HIDD + n_col] = v0;
            OutF[((size_t)(b * 32 + m0 + 16)) * HIDD + n_col] = v1;
        }
    }
}

extern "C" void kernel_launch(void* const* d_in, const int* in_sizes, int n_in,
                              void* d_out, int out_size, void* d_ws, size_t ws_size,
                              hipStream_t stream) {
    (void)in_sizes; (void)n_in; (void)out_size; (void)ws_size;
    const float* actions   = (const float*)d_in[0];
    const int*   timesteps = (const int*)d_in[1];
    const int*   cat_ids   = (const int*)d_in[2];
    const float* W1        = (const float*)d_in[3];
    const float* b1        = (const float*)d_in[4];
    const float* W2        = (const float*)d_in[5];
    const float* b2        = (const float*)d_in[6];
    const float* W3        = (const float*)d_in[7];
    const float* b3        = (const float*)d_in[8];
    float* out = (float*)d_out;

    unsigned short* xbuf = (unsigned short*)d_ws;                 // B*T*3072 bf16
    unsigned short* hbuf = xbuf + (size_t)NB * NT * 2 * HIDD;     // B*T*1536 bf16

    build_x_kernel<<<dim3(12, NT, NB), 256, 0, stream>>>(
        actions, timesteps, cat_ids, W1, b1, xbuf);

    gemm_cat_kernel<2 * HIDD, true><<<dim3(24, NB), 256, 0, stream>>>(
        xbuf, W2, b2, cat_ids, hbuf, nullptr);

    gemm_cat_kernel<HIDD, false><<<dim3(24, NB), 256, 0, stream>>>(
        hbuf, W3, b3, cat_ids, nullptr, out);
}